// Round 1
// baseline (292.023 us; speedup 1.0000x reference)
//
#include <hip/hip_runtime.h>
#include <stdint.h>

#define B_   2
#define C_   256
#define N_   4096
#define TD_  512
#define OC_  128   // C/2

typedef float  f32x4  __attribute__((ext_vector_type(4)));
typedef short  bf16x8 __attribute__((ext_vector_type(8)));
typedef unsigned short u16;

__device__ __forceinline__ u16 f2bf(float x){
  union { float f; uint32_t u; } v; v.f = x;
  uint32_t r = v.u + 0x7fffu + ((v.u >> 16) & 1u);
  return (u16)(r >> 16);
}
__device__ __forceinline__ float bflo(uint32_t u){
  union { uint32_t u; float f; } x; x.u = (u << 16); return x.f;
}
__device__ __forceinline__ float bfhi(uint32_t u){
  union { uint32_t u; float f; } x; x.u = (u & 0xffff0000u); return x.f;
}

__device__ __forceinline__ void gld_lds16(const void* g, void* l){
  __builtin_amdgcn_global_load_lds(
      (const __attribute__((address_space(1))) unsigned int*)g,
      (__attribute__((address_space(3))) unsigned int*)l,
      16, 0, 0);
}

// ---------------------------------------------------------------- K1: FiLM
__global__ __launch_bounds__(256) void k_film(
    const float* __restrict__ txt, const float* __restrict__ Wt, const float* __restrict__ bt,
    const float* __restrict__ Wg, const float* __restrict__ bg,
    const float* __restrict__ Wb, const float* __restrict__ bb,
    float* __restrict__ gamma, float* __restrict__ beta){
  int b = blockIdx.x, c = threadIdx.x;
  __shared__ float t_s[TD_];
  __shared__ float te[C_];
  for (int i = c; i < TD_; i += 256) t_s[i] = txt[b*TD_ + i];
  __syncthreads();
  float acc = bt[c];
  const float* w = Wt + (size_t)c*TD_;
  for (int k = 0; k < TD_; k++) acc += t_s[k]*w[k];
  te[c] = acc;
  __syncthreads();
  float g = bg[c], be = bb[c];
  const float* wg = Wg + (size_t)c*C_;
  const float* wbp = Wb + (size_t)c*C_;
  for (int k = 0; k < C_; k++){ float tv = te[k]; g += tv*wg[k]; be += tv*wbp[k]; }
  gamma[b*C_ + c] = g; beta[b*C_ + c] = be;
}

// ---------------------------------------- K2: mod + L2-normalize -> Sn NHWC bf16
__global__ __launch_bounds__(256) void k_build(
    const float* __restrict__ img, const float* __restrict__ gamma, const float* __restrict__ beta,
    u16* __restrict__ Sn){
  int b = blockIdx.y; int n0 = blockIdx.x*64;
  __shared__ float tile[C_][65];
  __shared__ float pss[4][64];
  __shared__ float inv[64];
  int t = threadIdx.x;
  int x = t & 63, cb = t >> 6;
  float ss = 0.f;
  for (int k = 0; k < 64; k++){
    int c = cb*64 + k;
    float v = img[((size_t)(b*C_ + c))*N_ + n0 + x];
    v = v*(1.f + gamma[b*C_ + c]) + beta[b*C_ + c];
    tile[c][x] = v;
    ss += v*v;
  }
  pss[cb][x] = ss;
  __syncthreads();
  if (t < 64){
    float s = pss[0][t] + pss[1][t] + pss[2][t] + pss[3][t];
    float nrm = sqrtf(s);
    inv[t] = 1.f / fmaxf(nrm, 1e-12f);
  }
  __syncthreads();
  for (int i = 0; i < 64; i++){
    int idx = i*256 + t;
    int c = idx & 255, nl = idx >> 8;
    Sn[((size_t)(b*N_ + n0 + nl))*C_ + c] = f2bf(tile[c][nl]*inv[nl]);
  }
}

// ------------------------------------------------- K2b: q from density, u=1
__global__ __launch_bounds__(256) void k_qinit(
    const float* __restrict__ dens, float* __restrict__ q, float* __restrict__ u){
  int b = blockIdx.x; int t = threadIdx.x;
  __shared__ float red[256];
  float s = 0.f;
  for (int i = t; i < N_; i += 256){ float v = fmaxf(dens[b*N_ + i], 0.f) + 1e-6f; s += v; }
  red[t] = s; __syncthreads();
  for (int o = 128; o; o >>= 1){ if (t < o) red[t] += red[t + o]; __syncthreads(); }
  float invs = 1.f / red[0];
  for (int i = t; i < N_; i += 256){
    float v = fmaxf(dens[b*N_ + i], 0.f) + 1e-6f;
    q[b*N_ + i] = v*invs;
    u[b*N_ + i] = 1.f;
  }
}

// -------------------------------------- repack Wo->bf16, Wc1 [O][I][3][3]->[s][O][I] bf16
__global__ __launch_bounds__(256) void k_repack(
    const float* __restrict__ Wo, const float* __restrict__ Wc1,
    u16* __restrict__ Wo_bf, u16* __restrict__ Wc1r){
  int i = blockIdx.x*256 + threadIdx.x;
  if (i < C_*C_) Wo_bf[i] = f2bf(Wo[i]);
  if (i < 9*OC_*C_){
    int s = i / (OC_*C_); int rem = i - s*(OC_*C_);
    int oc = rem >> 8; int ic = rem & 255;
    Wc1r[i] = f2bf(Wc1[((size_t)(oc*C_ + ic))*9 + s]);
  }
}

// ------------------------- K3: sim = Sn@Sn^T, K = exp((sim-1)/eps), bf16, transposed write
__global__ __launch_bounds__(256) void k_simK(const u16* __restrict__ Sn, u16* __restrict__ Kbf){
  int mt = blockIdx.x, nt = blockIdx.y, b = blockIdx.z;
  __shared__ u16 As[128*32];
  __shared__ u16 Bs[128*32];
  int t = threadIdx.x; int w = t >> 6; int l = t & 63;
  int wm = w >> 1, wn = w & 1;
  f32x4 acc[4][4] = {};
  const char* Abase = (const char*)(Sn + ((size_t)(b*N_ + mt*128))*C_);
  const char* Bbase = (const char*)(Sn + ((size_t)(b*N_ + nt*128))*C_);
  for (int ks = 0; ks < 8; ks++){
    __syncthreads();
    for (int r = 0; r < 2; r++){
      int off = r*4096 + w*1024;
      int eo = off + l*16;
      int row = eo >> 6, colb = eo & 63;
      gld_lds16(Abase + (size_t)row*512 + ks*64 + colb, (char*)As + off);
      gld_lds16(Bbase + (size_t)row*512 + ks*64 + colb, (char*)Bs + off);
    }
    __syncthreads();
    bf16x8 af[4], bfv[4];
    for (int i = 0; i < 4; i++){
      int rowa = wm*64 + i*16 + (l & 15);
      af[i] = *(const bf16x8*)(As + rowa*32 + (l >> 4)*8);
      int rowb = wn*64 + i*16 + (l & 15);
      bfv[i] = *(const bf16x8*)(Bs + rowb*32 + (l >> 4)*8);
    }
    for (int i = 0; i < 4; i++)
      for (int j = 0; j < 4; j++)
        acc[i][j] = __builtin_amdgcn_mfma_f32_16x16x32_bf16(af[i], bfv[j], acc[i][j], 0, 0, 0);
  }
  // K symmetric: write K[b][m'][m] (row=m contiguous per lane)
  for (int i = 0; i < 4; i++)
    for (int j = 0; j < 4; j++){
      int m0 = mt*128 + wm*64 + i*16 + ((l >> 4) << 2);
      int mp = nt*128 + wn*64 + j*16 + (l & 15);
      ushort4 pk;
      pk.x = f2bf(__expf((acc[i][j][0] - 1.f)*20.f));
      pk.y = f2bf(__expf((acc[i][j][1] - 1.f)*20.f));
      pk.z = f2bf(__expf((acc[i][j][2] - 1.f)*20.f));
      pk.w = f2bf(__expf((acc[i][j][3] - 1.f)*20.f));
      *(ushort4*)(Kbf + ((size_t)(b*N_ + mp))*N_ + m0) = pk;
    }
}

// -------------------------------- K4: Sinkhorn matvec, out = marg/(K@x + 1e-8)
__global__ __launch_bounds__(256) void k_matvec(
    const u16* __restrict__ Kbf, const float* __restrict__ x,
    const float* __restrict__ q, float* __restrict__ out, int use_q){
  int w = threadIdx.x >> 6, l = threadIdx.x & 63;
  int row = blockIdx.x*4 + w;          // b*4096+m
  int b = row >> 12;
  const u16* kp = Kbf + (size_t)row*N_;
  const float* xp = x + (size_t)b*N_;
  float s = 0.f;
  for (int it = 0; it < 8; it++){
    int n0 = it*512 + l*8;
    uint4 kv = *(const uint4*)(kp + n0);
    float4 x0 = *(const float4*)(xp + n0);
    float4 x1 = *(const float4*)(xp + n0 + 4);
    s += bflo(kv.x)*x0.x + bfhi(kv.x)*x0.y + bflo(kv.y)*x0.z + bfhi(kv.y)*x0.w;
    s += bflo(kv.z)*x1.x + bfhi(kv.z)*x1.y + bflo(kv.w)*x1.z + bfhi(kv.w)*x1.w;
  }
  for (int o = 32; o; o >>= 1) s += __shfl_down(s, o);
  if (l == 0){
    float marg = use_q ? q[row] : (1.f/(float)N_);
    out[row] = marg / (s + 1e-8f);
  }
}

// ----------------- K5: uS_chw[b][c][n] = bf16((img*(1+g)+b) * u[n])  (CHW bf16)
__global__ __launch_bounds__(256) void k_uS(
    const float* __restrict__ img, const float* __restrict__ gamma, const float* __restrict__ beta,
    const float* __restrict__ u, u16* __restrict__ uS){
  size_t i = ((size_t)blockIdx.x*256 + threadIdx.x)*4;
  int n = (int)(i & (N_ - 1));
  size_t bc = i >> 12;
  int b = (int)(bc >> 8);
  float gm = 1.f + gamma[bc];
  float bt = beta[bc];
  float4 v  = *(const float4*)(img + i);
  float4 uu = *(const float4*)(u + (size_t)b*N_ + n);
  ushort4 o;
  o.x = f2bf((v.x*gm + bt)*uu.x);
  o.y = f2bf((v.y*gm + bt)*uu.y);
  o.z = f2bf((v.z*gm + bt)*uu.z);
  o.w = f2bf((v.w*gm + bt)*uu.w);
  *(ushort4*)(uS + i) = o;
}

// --------- K6: fused[m][c] = v[m] * sum_n K[m,n] uS[c,n]  (D[row=c,col=m], NHWC out)
__global__ __launch_bounds__(256) void k_fused(
    const u16* __restrict__ Kbf, const u16* __restrict__ uS,
    const float* __restrict__ vvec, u16* __restrict__ fused){
  int ct = blockIdx.x, mt = blockIdx.y, b = blockIdx.z;
  __shared__ u16 As[64*32];
  __shared__ u16 Bs[128*32];
  int t = threadIdx.x, w = t >> 6, l = t & 63;
  int wm = w >> 1, wn = w & 1;
  f32x4 acc[2][4] = {};
  const char* Ab = (const char*)(uS  + ((size_t)(b*C_ + ct*64))*N_);
  const char* Bb = (const char*)(Kbf + ((size_t)(b*N_ + mt*128))*N_);
  for (int ks = 0; ks < 128; ks++){
    __syncthreads();
    {
      int off = w*1024;
      int eo = off + l*16;
      int row = eo >> 6, colb = eo & 63;
      gld_lds16(Ab + (size_t)row*8192 + ks*64 + colb, (char*)As + off);
    }
    for (int r = 0; r < 2; r++){
      int off = r*4096 + w*1024;
      int eo = off + l*16;
      int row = eo >> 6, colb = eo & 63;
      gld_lds16(Bb + (size_t)row*8192 + ks*64 + colb, (char*)Bs + off);
    }
    __syncthreads();
    bf16x8 af[2], bfv[4];
    for (int i = 0; i < 2; i++){
      int rowa = wm*32 + i*16 + (l & 15);
      af[i] = *(const bf16x8*)(As + rowa*32 + (l >> 4)*8);
    }
    for (int j = 0; j < 4; j++){
      int rowb = wn*64 + j*16 + (l & 15);
      bfv[j] = *(const bf16x8*)(Bs + rowb*32 + (l >> 4)*8);
    }
    for (int i = 0; i < 2; i++)
      for (int j = 0; j < 4; j++)
        acc[i][j] = __builtin_amdgcn_mfma_f32_16x16x32_bf16(af[i], bfv[j], acc[i][j], 0, 0, 0);
  }
  for (int j = 0; j < 4; j++){
    int m = mt*128 + wn*64 + j*16 + (l & 15);
    float vm = vvec[b*N_ + m];
    for (int i = 0; i < 2; i++){
      int c0 = ct*64 + wm*32 + i*16 + ((l >> 4) << 2);
      ushort4 pk;
      pk.x = f2bf(acc[i][j][0]*vm);
      pk.y = f2bf(acc[i][j][1]*vm);
      pk.z = f2bf(acc[i][j][2]*vm);
      pk.w = f2bf(acc[i][j][3]*vm);
      *(ushort4*)(fused + ((size_t)(b*N_ + m))*C_ + c0) = pk;
    }
  }
}

// -------- K7: out[b][o][n] = img + sum_c Wo[o,c] fused[n,c] + bo  (direct-global frags)
__global__ __launch_bounds__(256) void k_outproj(
    const u16* __restrict__ fused, const u16* __restrict__ Wo_bf,
    const float* __restrict__ img, const float* __restrict__ bo, float* __restrict__ out){
  int nt = blockIdx.x, ot = blockIdx.y, b = blockIdx.z;
  int t = threadIdx.x, w = t >> 6, l = t & 63;
  int wm = w >> 1, wn = w & 1;
  f32x4 acc[4][2] = {};
  for (int kc = 0; kc < 8; kc++){
    bf16x8 af[4], bfv[2];
    for (int i = 0; i < 4; i++){
      int n = nt*128 + wm*64 + i*16 + (l & 15);
      af[i] = *(const bf16x8*)(fused + ((size_t)(b*N_ + n))*C_ + kc*32 + (l >> 4)*8);
    }
    for (int j = 0; j < 2; j++){
      int o = ot*64 + wn*32 + j*16 + (l & 15);
      bfv[j] = *(const bf16x8*)(Wo_bf + (size_t)o*C_ + kc*32 + (l >> 4)*8);
    }
    for (int i = 0; i < 4; i++)
      for (int j = 0; j < 2; j++)
        acc[i][j] = __builtin_amdgcn_mfma_f32_16x16x32_bf16(af[i], bfv[j], acc[i][j], 0, 0, 0);
  }
  for (int i = 0; i < 4; i++)
    for (int j = 0; j < 2; j++){
      int o = ot*64 + wn*32 + j*16 + (l & 15);
      int n = nt*128 + wm*64 + i*16 + ((l >> 4) << 2);
      size_t a = ((size_t)(b*C_ + o))*N_ + n;
      float4 iv = *(const float4*)(img + a);
      float bov = bo[o];
      float4 r;
      r.x = iv.x + acc[i][j][0] + bov;
      r.y = iv.y + acc[i][j][1] + bov;
      r.z = iv.z + acc[i][j][2] + bov;
      r.w = iv.w + acc[i][j][3] + bov;
      *(float4*)(out + a) = r;
    }
}

// ------------------------------- K7b: NCHW f32 -> NHWC bf16 transpose of out_feat
__global__ __launch_bounds__(256) void k_nhwc(const float* __restrict__ out, u16* __restrict__ out_bf){
  int b = blockIdx.y, n0 = blockIdx.x*64;
  __shared__ float tile[C_][65];
  int t = threadIdx.x;
  int x = t & 63, cb = t >> 6;
  for (int k = 0; k < 64; k++){
    int c = cb*64 + k;
    tile[c][x] = out[((size_t)(b*C_ + c))*N_ + n0 + x];
  }
  __syncthreads();
  for (int i = 0; i < 64; i++){
    int idx = i*256 + t;
    int c = idx & 255, nl = idx >> 8;
    out_bf[((size_t)(b*N_ + n0 + nl))*C_ + c] = f2bf(tile[c][nl]);
  }
}

// ---------------- K8: conv3x3 SAME via 9-shift implicit GEMM, h NHWC f32 (+bc1)
__global__ __launch_bounds__(256) void k_conv(
    const u16* __restrict__ out_bf, const u16* __restrict__ Wc1r,
    const float* __restrict__ bc1, float* __restrict__ h){
  int ot = blockIdx.x, pt = blockIdx.y, b = blockIdx.z;
  int t = threadIdx.x, w = t >> 6, l = t & 63;
  int wm = w >> 1, wn = w & 1;
  f32x4 acc[2][2] = {};
  int pbase = pt*64 + wn*32;
  for (int s = 0; s < 9; s++){
    int dy = s/3 - 1, dx = s - (s/3)*3 - 1;
    for (int kc = 0; kc < 8; kc++){
      bf16x8 af[2], bfv[2];
      for (int i = 0; i < 2; i++){
        int oc = ot*64 + wm*32 + i*16 + (l & 15);
        af[i] = *(const bf16x8*)(Wc1r + ((size_t)(s*OC_ + oc))*C_ + kc*32 + (l >> 4)*8);
      }
      for (int j = 0; j < 2; j++){
        int p = pbase + j*16 + (l & 15);
        int y = (p >> 6) + dy, x = (p & 63) + dx;
        bf16x8 v = {0,0,0,0,0,0,0,0};
        if ((unsigned)y < 64u && (unsigned)x < 64u)
          v = *(const bf16x8*)(out_bf + ((size_t)(b*N_ + y*64 + x))*C_ + kc*32 + (l >> 4)*8);
        bfv[j] = v;
      }
      for (int i = 0; i < 2; i++)
        for (int j = 0; j < 2; j++)
          acc[i][j] = __builtin_amdgcn_mfma_f32_16x16x32_bf16(af[i], bfv[j], acc[i][j], 0, 0, 0);
    }
  }
  for (int i = 0; i < 2; i++)
    for (int j = 0; j < 2; j++){
      int p = pt*64 + wn*32 + j*16 + (l & 15);
      int oc = ot*64 + wm*32 + i*16 + ((l >> 4) << 2);
      float4 bc = *(const float4*)(bc1 + oc);
      float4 r;
      r.x = acc[i][j][0] + bc.x;
      r.y = acc[i][j][1] + bc.y;
      r.z = acc[i][j][2] + bc.z;
      r.w = acc[i][j][3] + bc.w;
      *(float4*)(h + ((size_t)(b*N_ + p))*OC_ + oc) = r;
    }
}

// -------------------------------------------- K9a: BN partial sums over 128-row chunks
__global__ __launch_bounds__(256) void k_stats(
    const float* __restrict__ h, float* __restrict__ pSum, float* __restrict__ pSsq){
  int blk = blockIdx.x;     // 64 blocks x 128 rows
  int t = threadIdx.x; int c = t & 127, half = t >> 7;
  __shared__ float s1[256], s2[256];
  float a = 0.f, b2 = 0.f;
  int r0 = blk*128 + half*64;
  for (int r = 0; r < 64; r++){
    float v = h[((size_t)(r0 + r))*OC_ + c];
    a += v; b2 += v*v;
  }
  s1[t] = a; s2[t] = b2;
  __syncthreads();
  if (t < 128){
    pSum[blk*128 + c] = s1[t] + s1[t + 128];
    pSsq[blk*128 + c] = s2[t] + s2[t + 128];
  }
}

// ------------------------------- K9b: finalize BN -> scale/shift per channel
__global__ void k_bnfin(
    const float* __restrict__ pSum, const float* __restrict__ pSsq,
    const float* __restrict__ bn_g, const float* __restrict__ bn_b, float* __restrict__ scsh){
  int c = threadIdx.x;   // 128
  float s = 0.f, ss = 0.f;
  for (int k = 0; k < 64; k++){ s += pSum[k*128 + c]; ss += pSsq[k*128 + c]; }
  float m = s * (1.f/8192.f);
  float var = ss * (1.f/8192.f) - m*m;
  float sc = bn_g[c] * rsqrtf(var + 1e-5f);
  scsh[c*2]   = sc;
  scsh[c*2+1] = bn_b[c] - m*sc;
}

// ------------------------- K10: relu(h*sc+sh) -> 1x1 conv (2 ch) -> heatmap NCHW
__global__ __launch_bounds__(256) void k_head(
    const float* __restrict__ h, const float* __restrict__ scsh,
    const float* __restrict__ Wc2, const float* __restrict__ bc2, float* __restrict__ hm){
  __shared__ float sc[128], sh[128], w0[128], w1[128];
  int t = threadIdx.x;
  if (t < 128){
    sc[t] = scsh[t*2]; sh[t] = scsh[t*2+1];
    w0[t] = Wc2[t];    w1[t] = Wc2[128 + t];
  }
  __syncthreads();
  int n = blockIdx.x*256 + t;          // 0..8191 = b*4096+p
  const float* hp = h + (size_t)n*OC_;
  float a0 = bc2[0], a1 = bc2[1];
  for (int c4 = 0; c4 < 32; c4++){
    float4 hv = *(const float4*)(hp + c4*4);
    int c = c4*4;
    float r;
    r = fmaxf(hv.x*sc[c]   + sh[c],   0.f); a0 += w0[c]*r;   a1 += w1[c]*r;
    r = fmaxf(hv.y*sc[c+1] + sh[c+1], 0.f); a0 += w0[c+1]*r; a1 += w1[c+1]*r;
    r = fmaxf(hv.z*sc[c+2] + sh[c+2], 0.f); a0 += w0[c+2]*r; a1 += w1[c+2]*r;
    r = fmaxf(hv.w*sc[c+3] + sh[c+3], 0.f); a0 += w0[c+3]*r; a1 += w1[c+3]*r;
  }
  int b = n >> 12, p = n & 4095;
  hm[((size_t)(b*2 + 0))*N_ + p] = a0;
  hm[((size_t)(b*2 + 1))*N_ + p] = a1;
}

// ================================================================ launcher
extern "C" void kernel_launch(void* const* d_in, const int* in_sizes, int n_in,
                              void* d_out, int out_size, void* d_ws, size_t ws_size,
                              hipStream_t stream){
  const float* img  = (const float*)d_in[0];
  const float* txt  = (const float*)d_in[1];
  const float* dens = (const float*)d_in[2];
  const float* Wt   = (const float*)d_in[3];
  const float* bt   = (const float*)d_in[4];
  const float* Wg   = (const float*)d_in[5];
  const float* bg   = (const float*)d_in[6];
  const float* Wb   = (const float*)d_in[7];
  const float* bb   = (const float*)d_in[8];
  const float* Wo   = (const float*)d_in[9];
  const float* bo   = (const float*)d_in[10];
  const float* Wc1  = (const float*)d_in[11];
  const float* bc1  = (const float*)d_in[12];
  const float* bng  = (const float*)d_in[13];
  const float* bnb  = (const float*)d_in[14];
  const float* Wc2  = (const float*)d_in[15];
  const float* bc2  = (const float*)d_in[16];

  char* ws = (char*)d_ws;
  // workspace layout (bytes)
  u16*   Kbf    = (u16*)  (ws + 0);                       // 67,108,864
  u16*   Sn     = (u16*)  (ws + 67108864);                //  4,194,304
  u16*   uS     = (u16*)  (ws + 71303168);                //  4,194,304
  u16*   fused  = (u16*)  (ws + 75497472);                //  4,194,304
  u16*   out_bf = (u16*)  (ws + 79691776);                //  4,194,304
  float* hbuf   = (float*)(ws + 83886080);                //  4,194,304
  float* gamma  = (float*)(ws + 88080384);                //      2,048
  float* beta   = (float*)(ws + 88082432);                //      2,048
  float* q      = (float*)(ws + 88084480);                //     32,768
  float* u      = (float*)(ws + 88117248);                //     32,768
  float* v      = (float*)(ws + 88150016);                //     32,768
  u16*   Wo_bf  = (u16*)  (ws + 88182784);                //    131,072
  u16*   Wc1r   = (u16*)  (ws + 88313856);                //    589,824
  float* pSum   = (float*)(ws + 88903680);                //     32,768
  float* pSsq   = (float*)(ws + 88936448);                //     32,768
  float* scsh   = (float*)(ws + 88969216);                //      1,024

  float* outp = (float*)d_out;                 // [2,256,64,64]
  float* hm   = outp + 2*C_*N_;                // [2,2,64,64]

  k_film  <<<2, 256, 0, stream>>>(txt, Wt, bt, Wg, bg, Wb, bb, gamma, beta);
  k_build <<<dim3(64,2), 256, 0, stream>>>(img, gamma, beta, Sn);
  k_qinit <<<2, 256, 0, stream>>>(dens, q, u);
  k_repack<<<1152, 256, 0, stream>>>(Wo, Wc1, Wo_bf, Wc1r);
  k_simK  <<<dim3(32,32,2), 256, 0, stream>>>(Sn, Kbf);
  for (int it = 0; it < 3; it++){
    k_matvec<<<2048, 256, 0, stream>>>(Kbf, u, q, v, 1);
    k_matvec<<<2048, 256, 0, stream>>>(Kbf, v, q, u, 0);
  }
  k_uS    <<<2048, 256, 0, stream>>>(img, gamma, beta, u, uS);
  k_fused <<<dim3(4,32,2), 256, 0, stream>>>(Kbf, uS, v, fused);
  k_outproj<<<dim3(32,4,2), 256, 0, stream>>>(fused, Wo_bf, img, bo, outp);
  k_nhwc  <<<dim3(64,2), 256, 0, stream>>>(outp, out_bf);
  k_conv  <<<dim3(2,64,2), 256, 0, stream>>>(out_bf, Wc1r, bc1, hbuf);
  k_stats <<<64, 256, 0, stream>>>(hbuf, pSum, pSsq);
  k_bnfin <<<1, 128, 0, stream>>>(pSum, pSsq, bng, bnb, scsh);
  k_head  <<<32, 256, 0, stream>>>(hbuf, scsh, Wc2, bc2, hm);
}

// Round 2
// 255.481 us; speedup vs baseline: 1.1430x; 1.1430x over previous
//
#include <hip/hip_runtime.h>
#include <stdint.h>

#define B_   2
#define C_   256
#define N_   4096
#define TD_  512
#define OC_  128   // C/2

typedef float  f32x4  __attribute__((ext_vector_type(4)));
typedef short  bf16x8 __attribute__((ext_vector_type(8)));
typedef unsigned short u16;

__device__ __forceinline__ u16 f2bf(float x){
  union { float f; uint32_t u; } v; v.f = x;
  uint32_t r = v.u + 0x7fffu + ((v.u >> 16) & 1u);
  return (u16)(r >> 16);
}
__device__ __forceinline__ float bflo(uint32_t u){
  union { uint32_t u; float f; } x; x.u = (u << 16); return x.f;
}
__device__ __forceinline__ float bfhi(uint32_t u){
  union { uint32_t u; float f; } x; x.u = (u & 0xffff0000u); return x.f;
}

__device__ __forceinline__ void gld_lds16(const void* g, void* l){
  __builtin_amdgcn_global_load_lds(
      (const __attribute__((address_space(1))) unsigned int*)g,
      (__attribute__((address_space(3))) unsigned int*)l,
      16, 0, 0);
}

// ---------------------------------------------------------------- K1: FiLM
__global__ __launch_bounds__(256) void k_film(
    const float* __restrict__ txt, const float* __restrict__ Wt, const float* __restrict__ bt,
    const float* __restrict__ Wg, const float* __restrict__ bg,
    const float* __restrict__ Wb, const float* __restrict__ bb,
    float* __restrict__ gamma, float* __restrict__ beta){
  int b = blockIdx.x, c = threadIdx.x;
  __shared__ float t_s[TD_];
  __shared__ float te[C_];
  for (int i = c; i < TD_; i += 256) t_s[i] = txt[b*TD_ + i];
  __syncthreads();
  float acc = bt[c];
  const float* w = Wt + (size_t)c*TD_;
  for (int k = 0; k < TD_; k++) acc += t_s[k]*w[k];
  te[c] = acc;
  __syncthreads();
  float g = bg[c], be = bb[c];
  const float* wg = Wg + (size_t)c*C_;
  const float* wbp = Wb + (size_t)c*C_;
  for (int k = 0; k < C_; k++){ float tv = te[k]; g += tv*wg[k]; be += tv*wbp[k]; }
  gamma[b*C_ + c] = g; beta[b*C_ + c] = be;
}

// ---------------------------------------- K2: mod + L2-normalize -> Sn NHWC bf16
__global__ __launch_bounds__(256) void k_build(
    const float* __restrict__ img, const float* __restrict__ gamma, const float* __restrict__ beta,
    u16* __restrict__ Sn){
  int b = blockIdx.y; int n0 = blockIdx.x*64;
  __shared__ float tile[C_][65];
  __shared__ float pss[4][64];
  __shared__ float inv[64];
  int t = threadIdx.x;
  int x = t & 63, cb = t >> 6;
  float ss = 0.f;
  for (int k = 0; k < 64; k++){
    int c = cb*64 + k;
    float v = img[((size_t)(b*C_ + c))*N_ + n0 + x];
    v = v*(1.f + gamma[b*C_ + c]) + beta[b*C_ + c];
    tile[c][x] = v;
    ss += v*v;
  }
  pss[cb][x] = ss;
  __syncthreads();
  if (t < 64){
    float s = pss[0][t] + pss[1][t] + pss[2][t] + pss[3][t];
    float nrm = sqrtf(s);
    inv[t] = 1.f / fmaxf(nrm, 1e-12f);
  }
  __syncthreads();
  for (int i = 0; i < 64; i++){
    int idx = i*256 + t;
    int c = idx & 255, nl = idx >> 8;
    Sn[((size_t)(b*N_ + n0 + nl))*C_ + c] = f2bf(tile[c][nl]*inv[nl]);
  }
}

// ------------------------------------------------- K2b: q from density, u=1
__global__ __launch_bounds__(256) void k_qinit(
    const float* __restrict__ dens, float* __restrict__ q, float* __restrict__ u){
  int b = blockIdx.x; int t = threadIdx.x;
  __shared__ float red[256];
  float s = 0.f;
  for (int i = t; i < N_; i += 256){ float v = fmaxf(dens[b*N_ + i], 0.f) + 1e-6f; s += v; }
  red[t] = s; __syncthreads();
  for (int o = 128; o; o >>= 1){ if (t < o) red[t] += red[t + o]; __syncthreads(); }
  float invs = 1.f / red[0];
  for (int i = t; i < N_; i += 256){
    float v = fmaxf(dens[b*N_ + i], 0.f) + 1e-6f;
    q[b*N_ + i] = v*invs;
    u[b*N_ + i] = 1.f;
  }
}

// -------------------------------------- repack Wo->bf16, Wc1 [O][I][3][3]->[s][O][I] bf16
__global__ __launch_bounds__(256) void k_repack(
    const float* __restrict__ Wo, const float* __restrict__ Wc1,
    u16* __restrict__ Wo_bf, u16* __restrict__ Wc1r){
  int i = blockIdx.x*256 + threadIdx.x;
  if (i < C_*C_) Wo_bf[i] = f2bf(Wo[i]);
  if (i < 9*OC_*C_){
    int s = i / (OC_*C_); int rem = i - s*(OC_*C_);
    int oc = rem >> 8; int ic = rem & 255;
    Wc1r[i] = f2bf(Wc1[((size_t)(oc*C_ + ic))*9 + s]);
  }
}

// ------------------------- K3: sim = Sn@Sn^T, K = exp((sim-1)/eps), bf16, transposed write
// BK=64 (4 K-steps), 128x128 tile, m97-style staging.
__global__ __launch_bounds__(256) void k_simK(const u16* __restrict__ Sn, u16* __restrict__ Kbf){
  int mt = blockIdx.x, nt = blockIdx.y, b = blockIdx.z;
  __shared__ u16 As[128*64];   // 16 KB
  __shared__ u16 Bs[128*64];   // 16 KB
  int t = threadIdx.x; int w = t >> 6; int l = t & 63;
  int wm = w >> 1, wn = w & 1;
  f32x4 acc[4][4] = {};
  const char* Ab = (const char*)(Sn + ((size_t)(b*N_ + mt*128))*C_);
  const char* Bb = (const char*)(Sn + ((size_t)(b*N_ + nt*128))*C_);
  for (int step = 0; step < 4; step++){
    __syncthreads();
    for (int r = 0; r < 4; r++){
      int off = r*4096 + t*16;
      int row = off >> 7, col = off & 127;
      gld_lds16(Ab + (size_t)row*512 + step*128 + col, (char*)As + off);
      gld_lds16(Bb + (size_t)row*512 + step*128 + col, (char*)Bs + off);
    }
    __syncthreads();
    for (int kk = 0; kk < 2; kk++){
      bf16x8 af[4], bfv[4];
      for (int i = 0; i < 4; i++){
        int rowa = wm*64 + i*16 + (l & 15);
        af[i]  = *(const bf16x8*)((const u16*)As + rowa*64 + kk*32 + (l >> 4)*8);
        int rowb = wn*64 + i*16 + (l & 15);
        bfv[i] = *(const bf16x8*)((const u16*)Bs + rowb*64 + kk*32 + (l >> 4)*8);
      }
      for (int i = 0; i < 4; i++)
        for (int j = 0; j < 4; j++)
          acc[i][j] = __builtin_amdgcn_mfma_f32_16x16x32_bf16(af[i], bfv[j], acc[i][j], 0, 0, 0);
    }
  }
  // K symmetric: write K[b][m'][m] (row=m contiguous per lane)
  for (int i = 0; i < 4; i++)
    for (int j = 0; j < 4; j++){
      int m0 = mt*128 + wm*64 + i*16 + ((l >> 4) << 2);
      int mp = nt*128 + wn*64 + j*16 + (l & 15);
      ushort4 pk;
      pk.x = f2bf(__expf((acc[i][j][0] - 1.f)*20.f));
      pk.y = f2bf(__expf((acc[i][j][1] - 1.f)*20.f));
      pk.z = f2bf(__expf((acc[i][j][2] - 1.f)*20.f));
      pk.w = f2bf(__expf((acc[i][j][3] - 1.f)*20.f));
      *(ushort4*)(Kbf + ((size_t)(b*N_ + mp))*N_ + m0) = pk;
    }
}

// -------------------------------- K4: Sinkhorn matvec, out = marg/(K@x + 1e-8)
__global__ __launch_bounds__(256) void k_matvec(
    const u16* __restrict__ Kbf, const float* __restrict__ x,
    const float* __restrict__ q, float* __restrict__ out, int use_q){
  int w = threadIdx.x >> 6, l = threadIdx.x & 63;
  int row = blockIdx.x*4 + w;          // b*4096+m
  int b = row >> 12;
  const u16* kp = Kbf + (size_t)row*N_;
  const float* xp = x + (size_t)b*N_;
  float s = 0.f;
  for (int it = 0; it < 8; it++){
    int n0 = it*512 + l*8;
    uint4 kv = *(const uint4*)(kp + n0);
    float4 x0 = *(const float4*)(xp + n0);
    float4 x1 = *(const float4*)(xp + n0 + 4);
    s += bflo(kv.x)*x0.x + bfhi(kv.x)*x0.y + bflo(kv.y)*x0.z + bfhi(kv.y)*x0.w;
    s += bflo(kv.z)*x1.x + bfhi(kv.z)*x1.y + bflo(kv.w)*x1.z + bfhi(kv.w)*x1.w;
  }
  for (int o = 32; o; o >>= 1) s += __shfl_down(s, o);
  if (l == 0){
    float marg = use_q ? q[row] : (1.f/(float)N_);
    out[row] = marg / (s + 1e-8f);
  }
}

// ----------------- K5: uS_chw[b][c][n] = bf16((img*(1+g)+b) * u[n])  (CHW bf16)
__global__ __launch_bounds__(256) void k_uS(
    const float* __restrict__ img, const float* __restrict__ gamma, const float* __restrict__ beta,
    const float* __restrict__ u, u16* __restrict__ uS){
  size_t i = ((size_t)blockIdx.x*256 + threadIdx.x)*4;
  int n = (int)(i & (N_ - 1));
  size_t bc = i >> 12;
  int b = (int)(bc >> 8);
  float gm = 1.f + gamma[bc];
  float bt = beta[bc];
  float4 v  = *(const float4*)(img + i);
  float4 uu = *(const float4*)(u + (size_t)b*N_ + n);
  ushort4 o;
  o.x = f2bf((v.x*gm + bt)*uu.x);
  o.y = f2bf((v.y*gm + bt)*uu.y);
  o.z = f2bf((v.z*gm + bt)*uu.z);
  o.w = f2bf((v.w*gm + bt)*uu.w);
  *(ushort4*)(uS + i) = o;
}

// --------- K6: split-K GEMM partials: part[ks][b][m][c] (f16) = sum_{n in chunk} K[m,n]*uS[c,n]
// tile 128m x 128c, BK=64, grid (ct*4+ks? -> x: ct in bit0, ks in bits1.., mt, b) = 512 blocks
__global__ __launch_bounds__(256) void k_fused_part(
    const u16* __restrict__ Kbf, const u16* __restrict__ uS, _Float16* __restrict__ part){
  int ct = blockIdx.x & 1, ks = blockIdx.x >> 1;   // ct 0..1, ks 0..3
  int mt = blockIdx.y, b = blockIdx.z;
  __shared__ u16 As[128*64];   // uS c-rows, 16 KB
  __shared__ u16 Bs[128*64];   // K  m-rows, 16 KB
  int t = threadIdx.x, w = t >> 6, l = t & 63;
  int wc = w >> 1, wm = w & 1;
  f32x4 acc[4][4] = {};
  const char* Ab = (const char*)(uS  + ((size_t)(b*C_ + ct*128))*N_ + ks*1024);
  const char* Bb = (const char*)(Kbf + ((size_t)(b*N_ + mt*128))*N_ + ks*1024);
  for (int step = 0; step < 16; step++){
    __syncthreads();
    for (int r = 0; r < 4; r++){
      int off = r*4096 + t*16;
      int row = off >> 7, col = off & 127;
      gld_lds16(Ab + (size_t)row*8192 + step*128 + col, (char*)As + off);
      gld_lds16(Bb + (size_t)row*8192 + step*128 + col, (char*)Bs + off);
    }
    __syncthreads();
    for (int kk = 0; kk < 2; kk++){
      bf16x8 af[4], bfv[4];
      for (int i = 0; i < 4; i++){
        int rowa = wc*64 + i*16 + (l & 15);
        af[i]  = *(const bf16x8*)((const u16*)As + rowa*64 + kk*32 + (l >> 4)*8);
        int rowb = wm*64 + i*16 + (l & 15);
        bfv[i] = *(const bf16x8*)((const u16*)Bs + rowb*64 + kk*32 + (l >> 4)*8);
      }
      for (int i = 0; i < 4; i++)
        for (int j = 0; j < 4; j++)
          acc[i][j] = __builtin_amdgcn_mfma_f32_16x16x32_bf16(af[i], bfv[j], acc[i][j], 0, 0, 0);
    }
  }
  _Float16* pp = part + ((size_t)(ks*2 + b))*N_*C_;
  for (int i = 0; i < 4; i++)
    for (int j = 0; j < 4; j++){
      int c0 = ct*128 + wc*64 + i*16 + ((l >> 4) << 2);
      int m  = mt*128 + wm*64 + j*16 + (l & 15);
      union { _Float16 h[4]; ushort4 u; } pk;
      pk.h[0] = (_Float16)acc[i][j][0];
      pk.h[1] = (_Float16)acc[i][j][1];
      pk.h[2] = (_Float16)acc[i][j][2];
      pk.h[3] = (_Float16)acc[i][j][3];
      *(ushort4*)(pp + (size_t)m*C_ + c0) = pk.u;
    }
}

// -------------------- K6b: reduce 4 split-K partials, scale by v[m], emit bf16 fused[n][c]
__global__ __launch_bounds__(256) void k_reduce(
    const _Float16* __restrict__ part, const float* __restrict__ vvec, u16* __restrict__ fused){
  int idx = blockIdx.x*256 + threadIdx.x;       // 2048 blocks -> 524288 threads
  int c0 = (idx & 63) * 4;
  int bm = idx >> 6;                            // b*4096 + m
  int b = bm >> 12, m = bm & 4095;
  float vm = vvec[bm];
  float s0 = 0.f, s1 = 0.f, s2 = 0.f, s3 = 0.f;
  for (int sp = 0; sp < 4; sp++){
    union { ushort4 u; _Float16 h[4]; } pk;
    pk.u = *(const ushort4*)(part + (((size_t)(sp*2 + b))*N_ + m)*C_ + c0);
    s0 += (float)pk.h[0]; s1 += (float)pk.h[1];
    s2 += (float)pk.h[2]; s3 += (float)pk.h[3];
  }
  ushort4 o;
  o.x = f2bf(s0*vm); o.y = f2bf(s1*vm);
  o.z = f2bf(s2*vm); o.w = f2bf(s3*vm);
  *(ushort4*)(fused + (size_t)bm*C_ + c0) = o;
}

// -------- K7: out[b][o][n] = img + sum_c Wo[o,c] fused[n,c] + bo  (direct-global frags)
__global__ __launch_bounds__(256) void k_outproj(
    const u16* __restrict__ fused, const u16* __restrict__ Wo_bf,
    const float* __restrict__ img, const float* __restrict__ bo, float* __restrict__ out){
  int nt = blockIdx.x, ot = blockIdx.y, b = blockIdx.z;
  int t = threadIdx.x, w = t >> 6, l = t & 63;
  int wm = w >> 1, wn = w & 1;
  f32x4 acc[4][2] = {};
  for (int kc = 0; kc < 8; kc++){
    bf16x8 af[4], bfv[2];
    for (int i = 0; i < 4; i++){
      int n = nt*128 + wm*64 + i*16 + (l & 15);
      af[i] = *(const bf16x8*)(fused + ((size_t)(b*N_ + n))*C_ + kc*32 + (l >> 4)*8);
    }
    for (int j = 0; j < 2; j++){
      int o = ot*64 + wn*32 + j*16 + (l & 15);
      bfv[j] = *(const bf16x8*)(Wo_bf + (size_t)o*C_ + kc*32 + (l >> 4)*8);
    }
    for (int i = 0; i < 4; i++)
      for (int j = 0; j < 2; j++)
        acc[i][j] = __builtin_amdgcn_mfma_f32_16x16x32_bf16(af[i], bfv[j], acc[i][j], 0, 0, 0);
  }
  for (int i = 0; i < 4; i++)
    for (int j = 0; j < 2; j++){
      int o = ot*64 + wn*32 + j*16 + (l & 15);
      int n = nt*128 + wm*64 + i*16 + ((l >> 4) << 2);
      size_t a = ((size_t)(b*C_ + o))*N_ + n;
      float4 iv = *(const float4*)(img + a);
      float bov = bo[o];
      float4 r;
      r.x = iv.x + acc[i][j][0] + bov;
      r.y = iv.y + acc[i][j][1] + bov;
      r.z = iv.z + acc[i][j][2] + bov;
      r.w = iv.w + acc[i][j][3] + bov;
      *(float4*)(out + a) = r;
    }
}

// ------------------------------- K7b: NCHW f32 -> NHWC bf16 transpose of out_feat
__global__ __launch_bounds__(256) void k_nhwc(const float* __restrict__ out, u16* __restrict__ out_bf){
  int b = blockIdx.y, n0 = blockIdx.x*64;
  __shared__ float tile[C_][65];
  int t = threadIdx.x;
  int x = t & 63, cb = t >> 6;
  for (int k = 0; k < 64; k++){
    int c = cb*64 + k;
    tile[c][x] = out[((size_t)(b*C_ + c))*N_ + n0 + x];
  }
  __syncthreads();
  for (int i = 0; i < 64; i++){
    int idx = i*256 + t;
    int c = idx & 255, nl = idx >> 8;
    out_bf[((size_t)(b*N_ + n0 + nl))*C_ + c] = f2bf(tile[c][nl]);
  }
}

// ---------------- K8: conv3x3 SAME via 9-shift implicit GEMM, h NHWC f32 (+bc1)
__global__ __launch_bounds__(256) void k_conv(
    const u16* __restrict__ out_bf, const u16* __restrict__ Wc1r,
    const float* __restrict__ bc1, float* __restrict__ h){
  int ot = blockIdx.x, pt = blockIdx.y, b = blockIdx.z;
  int t = threadIdx.x, w = t >> 6, l = t & 63;
  int wm = w >> 1, wn = w & 1;
  f32x4 acc[2][2] = {};
  int pbase = pt*64 + wn*32;
  for (int s = 0; s < 9; s++){
    int dy = s/3 - 1, dx = s - (s/3)*3 - 1;
    for (int kc = 0; kc < 8; kc++){
      bf16x8 af[2], bfv[2];
      for (int i = 0; i < 2; i++){
        int oc = ot*64 + wm*32 + i*16 + (l & 15);
        af[i] = *(const bf16x8*)(Wc1r + ((size_t)(s*OC_ + oc))*C_ + kc*32 + (l >> 4)*8);
      }
      for (int j = 0; j < 2; j++){
        int p = pbase + j*16 + (l & 15);
        int y = (p >> 6) + dy, x = (p & 63) + dx;
        bf16x8 v = {0,0,0,0,0,0,0,0};
        if ((unsigned)y < 64u && (unsigned)x < 64u)
          v = *(const bf16x8*)(out_bf + ((size_t)(b*N_ + y*64 + x))*C_ + kc*32 + (l >> 4)*8);
        bfv[j] = v;
      }
      for (int i = 0; i < 2; i++)
        for (int j = 0; j < 2; j++)
          acc[i][j] = __builtin_amdgcn_mfma_f32_16x16x32_bf16(af[i], bfv[j], acc[i][j], 0, 0, 0);
    }
  }
  for (int i = 0; i < 2; i++)
    for (int j = 0; j < 2; j++){
      int p = pt*64 + wn*32 + j*16 + (l & 15);
      int oc = ot*64 + wm*32 + i*16 + ((l >> 4) << 2);
      float4 bc = *(const float4*)(bc1 + oc);
      float4 r;
      r.x = acc[i][j][0] + bc.x;
      r.y = acc[i][j][1] + bc.y;
      r.z = acc[i][j][2] + bc.z;
      r.w = acc[i][j][3] + bc.w;
      *(float4*)(h + ((size_t)(b*N_ + p))*OC_ + oc) = r;
    }
}

// -------------------------------------------- K9a: BN partial sums over 128-row chunks
__global__ __launch_bounds__(256) void k_stats(
    const float* __restrict__ h, float* __restrict__ pSum, float* __restrict__ pSsq){
  int blk = blockIdx.x;     // 64 blocks x 128 rows
  int t = threadIdx.x; int c = t & 127, half = t >> 7;
  __shared__ float s1[256], s2[256];
  float a = 0.f, b2 = 0.f;
  int r0 = blk*128 + half*64;
  for (int r = 0; r < 64; r++){
    float v = h[((size_t)(r0 + r))*OC_ + c];
    a += v; b2 += v*v;
  }
  s1[t] = a; s2[t] = b2;
  __syncthreads();
  if (t < 128){
    pSum[blk*128 + c] = s1[t] + s1[t + 128];
    pSsq[blk*128 + c] = s2[t] + s2[t + 128];
  }
}

// ------------------------------- K9b: finalize BN -> scale/shift per channel
__global__ void k_bnfin(
    const float* __restrict__ pSum, const float* __restrict__ pSsq,
    const float* __restrict__ bn_g, const float* __restrict__ bn_b, float* __restrict__ scsh){
  int c = threadIdx.x;   // 128
  float s = 0.f, ss = 0.f;
  for (int k = 0; k < 64; k++){ s += pSum[k*128 + c]; ss += pSsq[k*128 + c]; }
  float m = s * (1.f/8192.f);
  float var = ss * (1.f/8192.f) - m*m;
  float sc = bn_g[c] * rsqrtf(var + 1e-5f);
  scsh[c*2]   = sc;
  scsh[c*2+1] = bn_b[c] - m*sc;
}

// ------------------------- K10: relu(h*sc+sh) -> 1x1 conv (2 ch) -> heatmap NCHW
__global__ __launch_bounds__(256) void k_head(
    const float* __restrict__ h, const float* __restrict__ scsh,
    const float* __restrict__ Wc2, const float* __restrict__ bc2, float* __restrict__ hm){
  __shared__ float sc[128], sh[128], w0[128], w1[128];
  int t = threadIdx.x;
  if (t < 128){
    sc[t] = scsh[t*2]; sh[t] = scsh[t*2+1];
    w0[t] = Wc2[t];    w1[t] = Wc2[128 + t];
  }
  __syncthreads();
  int n = blockIdx.x*256 + t;          // 0..8191 = b*4096+p
  const float* hp = h + (size_t)n*OC_;
  float a0 = bc2[0], a1 = bc2[1];
  for (int c4 = 0; c4 < 32; c4++){
    float4 hv = *(const float4*)(hp + c4*4);
    int c = c4*4;
    float r;
    r = fmaxf(hv.x*sc[c]   + sh[c],   0.f); a0 += w0[c]*r;   a1 += w1[c]*r;
    r = fmaxf(hv.y*sc[c+1] + sh[c+1], 0.f); a0 += w0[c+1]*r; a1 += w1[c+1]*r;
    r = fmaxf(hv.z*sc[c+2] + sh[c+2], 0.f); a0 += w0[c+2]*r; a1 += w1[c+2]*r;
    r = fmaxf(hv.w*sc[c+3] + sh[c+3], 0.f); a0 += w0[c+3]*r; a1 += w1[c+3]*r;
  }
  int b = n >> 12, p = n & 4095;
  hm[((size_t)(b*2 + 0))*N_ + p] = a0;
  hm[((size_t)(b*2 + 1))*N_ + p] = a1;
}

// ================================================================ launcher
extern "C" void kernel_launch(void* const* d_in, const int* in_sizes, int n_in,
                              void* d_out, int out_size, void* d_ws, size_t ws_size,
                              hipStream_t stream){
  const float* img  = (const float*)d_in[0];
  const float* txt  = (const float*)d_in[1];
  const float* dens = (const float*)d_in[2];
  const float* Wt   = (const float*)d_in[3];
  const float* bt   = (const float*)d_in[4];
  const float* Wg   = (const float*)d_in[5];
  const float* bg   = (const float*)d_in[6];
  const float* Wb   = (const float*)d_in[7];
  const float* bb   = (const float*)d_in[8];
  const float* Wo   = (const float*)d_in[9];
  const float* bo   = (const float*)d_in[10];
  const float* Wc1  = (const float*)d_in[11];
  const float* bc1  = (const float*)d_in[12];
  const float* bng  = (const float*)d_in[13];
  const float* bnb  = (const float*)d_in[14];
  const float* Wc2  = (const float*)d_in[15];
  const float* bc2  = (const float*)d_in[16];

  char* ws = (char*)d_ws;
  // workspace layout (bytes) with lifetime overlays:
  //   [0, 67108864)            Kbf            (simK -> fused_part)
  //   [67108864, 83886080)     partH 16.7MB   (fused_part -> reduce)
  //       overlays: Sn @67108864 (build->simK, dead before partH written)
  //                 out_bf @67108864 (nhwc->conv, written after partH dead)
  //                 hbuf  @71303168 (conv->head, written after partH dead)
  //   [83886080, ...)          uS, fused_bf, smalls
  u16*      Kbf    = (u16*)     (ws + 0);
  _Float16* partH  = (_Float16*)(ws + 67108864);
  u16*      Sn     = (u16*)     (ws + 67108864);
  u16*      out_bf = (u16*)     (ws + 67108864);
  float*    hbuf   = (float*)   (ws + 71303168);
  u16*      uS     = (u16*)     (ws + 83886080);
  u16*      fused  = (u16*)     (ws + 88080384);
  float*    gamma  = (float*)   (ws + 92274688);
  float*    beta   = (float*)   (ws + 92276736);
  float*    q      = (float*)   (ws + 92278784);
  float*    u      = (float*)   (ws + 92311552);
  float*    v      = (float*)   (ws + 92344320);
  u16*      Wo_bf  = (u16*)     (ws + 92377088);
  u16*      Wc1r   = (u16*)     (ws + 92508160);
  float*    pSum   = (float*)   (ws + 93097984);
  float*    pSsq   = (float*)   (ws + 93130752);
  float*    scsh   = (float*)   (ws + 93163520);

  float* outp = (float*)d_out;                 // [2,256,64,64]
  float* hm   = outp + 2*C_*N_;                // [2,2,64,64]

  k_film  <<<2, 256, 0, stream>>>(txt, Wt, bt, Wg, bg, Wb, bb, gamma, beta);
  k_build <<<dim3(64,2), 256, 0, stream>>>(img, gamma, beta, Sn);
  k_qinit <<<2, 256, 0, stream>>>(dens, q, u);
  k_repack<<<1152, 256, 0, stream>>>(Wo, Wc1, Wo_bf, Wc1r);
  k_simK  <<<dim3(32,32,2), 256, 0, stream>>>(Sn, Kbf);
  for (int it = 0; it < 3; it++){
    k_matvec<<<2048, 256, 0, stream>>>(Kbf, u, q, v, 1);
    k_matvec<<<2048, 256, 0, stream>>>(Kbf, v, q, u, 0);
  }
  k_uS        <<<2048, 256, 0, stream>>>(img, gamma, beta, u, uS);
  k_fused_part<<<dim3(8,32,2), 256, 0, stream>>>(Kbf, uS, partH);
  k_reduce    <<<2048, 256, 0, stream>>>(partH, v, fused);
  k_outproj   <<<dim3(32,4,2), 256, 0, stream>>>(fused, Wo_bf, img, bo, outp);
  k_nhwc      <<<dim3(64,2), 256, 0, stream>>>(outp, out_bf);
  k_conv      <<<dim3(2,64,2), 256, 0, stream>>>(out_bf, Wc1r, bc1, hbuf);
  k_stats     <<<64, 256, 0, stream>>>(hbuf, pSum, pSsq);
  k_bnfin     <<<1, 128, 0, stream>>>(pSum, pSsq, bng, bnb, scsh);
  k_head      <<<32, 256, 0, stream>>>(hbuf, scsh, Wc2, bc2, hm);
}

// Round 3
// 215.518 us; speedup vs baseline: 1.3550x; 1.1854x over previous
//
#include <hip/hip_runtime.h>
#include <stdint.h>

#define B_   2
#define C_   256
#define N_   4096
#define TD_  512
#define OC_  128   // C/2

typedef float  f32x4  __attribute__((ext_vector_type(4)));
typedef short  bf16x8 __attribute__((ext_vector_type(8)));
typedef unsigned short u16;
typedef unsigned char  u8;

__device__ __forceinline__ u16 f2bf(float x){
  union { float f; uint32_t u; } v; v.f = x;
  uint32_t r = v.u + 0x7fffu + ((v.u >> 16) & 1u);
  return (u16)(r >> 16);
}
// f32 -> e5m2 byte (clamped, RNE via f16 high-byte truncation)
__device__ __forceinline__ uint32_t f2e5m2(float x){
  x = fminf(fmaxf(x, -57344.f), 57344.f);
  union { _Float16 h; u16 u; } c; c.h = (_Float16)x;
  uint32_t hb = c.u;
  return ((hb + 0x7fu + ((hb >> 8) & 1u)) >> 8) & 0xffu;
}
__device__ __forceinline__ float e5m2f(uint32_t byte){
  union { u16 u; _Float16 h; } c; c.u = (u16)(byte << 8);
  return (float)c.h;
}

__device__ __forceinline__ void gld_lds16(const void* g, void* l){
  __builtin_amdgcn_global_load_lds(
      (const __attribute__((address_space(1))) unsigned int*)g,
      (__attribute__((address_space(3))) unsigned int*)l,
      16, 0, 0);
}

// ---------------------------------------------------------------- K1: FiLM
__global__ __launch_bounds__(256) void k_film(
    const float* __restrict__ txt, const float* __restrict__ Wt, const float* __restrict__ bt,
    const float* __restrict__ Wg, const float* __restrict__ bg,
    const float* __restrict__ Wb, const float* __restrict__ bb,
    float* __restrict__ gamma, float* __restrict__ beta){
  int b = blockIdx.x, c = threadIdx.x;
  __shared__ float t_s[TD_];
  __shared__ float te[C_];
  for (int i = c; i < TD_; i += 256) t_s[i] = txt[b*TD_ + i];
  __syncthreads();
  float acc = bt[c];
  const float* w = Wt + (size_t)c*TD_;
  for (int k = 0; k < TD_; k++) acc += t_s[k]*w[k];
  te[c] = acc;
  __syncthreads();
  float g = bg[c], be = bb[c];
  const float* wg = Wg + (size_t)c*C_;
  const float* wbp = Wb + (size_t)c*C_;
  for (int k = 0; k < C_; k++){ float tv = te[k]; g += tv*wg[k]; be += tv*wbp[k]; }
  gamma[b*C_ + c] = g; beta[b*C_ + c] = be;
}

// ---------------------------------------- K2: mod + L2-normalize -> Sn NHWC bf16
__global__ __launch_bounds__(256) void k_build(
    const float* __restrict__ img, const float* __restrict__ gamma, const float* __restrict__ beta,
    u16* __restrict__ Sn){
  int b = blockIdx.y; int n0 = blockIdx.x*64;
  __shared__ float tile[C_][65];
  __shared__ float pss[4][64];
  __shared__ float inv[64];
  int t = threadIdx.x;
  int x = t & 63, cb = t >> 6;
  float ss = 0.f;
  for (int k = 0; k < 64; k++){
    int c = cb*64 + k;
    float v = img[((size_t)(b*C_ + c))*N_ + n0 + x];
    v = v*(1.f + gamma[b*C_ + c]) + beta[b*C_ + c];
    tile[c][x] = v;
    ss += v*v;
  }
  pss[cb][x] = ss;
  __syncthreads();
  if (t < 64){
    float s = pss[0][t] + pss[1][t] + pss[2][t] + pss[3][t];
    float nrm = sqrtf(s);
    inv[t] = 1.f / fmaxf(nrm, 1e-12f);
  }
  __syncthreads();
  for (int i = 0; i < 64; i++){
    int idx = i*256 + t;
    int c = idx & 255, nl = idx >> 8;
    Sn[((size_t)(b*N_ + n0 + nl))*C_ + c] = f2bf(tile[c][nl]*inv[nl]);
  }
}

// ------------------------------------------------- K2b: q from density, u=1
__global__ __launch_bounds__(256) void k_qinit(
    const float* __restrict__ dens, float* __restrict__ q, float* __restrict__ u){
  int b = blockIdx.x; int t = threadIdx.x;
  __shared__ float red[256];
  float s = 0.f;
  for (int i = t; i < N_; i += 256){ float v = fmaxf(dens[b*N_ + i], 0.f) + 1e-6f; s += v; }
  red[t] = s; __syncthreads();
  for (int o = 128; o; o >>= 1){ if (t < o) red[t] += red[t + o]; __syncthreads(); }
  float invs = 1.f / red[0];
  for (int i = t; i < N_; i += 256){
    float v = fmaxf(dens[b*N_ + i], 0.f) + 1e-6f;
    q[b*N_ + i] = v*invs;
    u[b*N_ + i] = 1.f;
  }
}

// -------------------------------------- repack Wo->bf16, Wc1 [O][I][3][3]->[s][O][I] bf16
__global__ __launch_bounds__(256) void k_repack(
    const float* __restrict__ Wo, const float* __restrict__ Wc1,
    u16* __restrict__ Wo_bf, u16* __restrict__ Wc1r){
  int i = blockIdx.x*256 + threadIdx.x;
  if (i < C_*C_) Wo_bf[i] = f2bf(Wo[i]);
  if (i < 9*OC_*C_){
    int s = i / (OC_*C_); int rem = i - s*(OC_*C_);
    int oc = rem >> 8; int ic = rem & 255;
    Wc1r[i] = f2bf(Wc1[((size_t)(oc*C_ + ic))*9 + s]);
  }
}

// ------------------------- K3: sim = Sn@Sn^T, K8 = e5m2(exp((sim-1)/eps))
// BK=64, 128x128 tile; T2 XOR-swizzled LDS (pre-swizzled gld source, rule 21);
// LDS-transpose epilogue -> fully coalesced 128B-row K8 writes.
__global__ __launch_bounds__(256) void k_simK(const u16* __restrict__ Sn, u8* __restrict__ K8){
  int mt = blockIdx.x, nt = blockIdx.y, b = blockIdx.z;
  __shared__ char smem[32768];   // As 16KB | Bs 16KB; epilogue reuses first 16KB as fp8 tile
  int t = threadIdx.x; int w = t >> 6; int l = t & 63;
  int wm = w >> 1, wn = w & 1;
  f32x4 acc[4][4] = {};
  const char* Ab = (const char*)(Sn + ((size_t)(b*N_ + mt*128))*C_);
  const char* Bb = (const char*)(Sn + ((size_t)(b*N_ + nt*128))*C_);
  for (int step = 0; step < 4; step++){
    __syncthreads();
    for (int r = 0; r < 4; r++){
      int off = r*4096 + t*16;
      int row = off >> 7;
      int col = (off & 127) ^ ((row & 7) << 4);   // inverse-swizzled source
      gld_lds16(Ab + (size_t)row*512 + step*128 + col, smem + off);
      gld_lds16(Bb + (size_t)row*512 + step*128 + col, smem + 16384 + off);
    }
    __syncthreads();
    for (int kk = 0; kk < 2; kk++){
      bf16x8 af[4], bfv[4];
      for (int i = 0; i < 4; i++){
        int ra = wm*64 + i*16 + (l & 15);
        af[i]  = *(const bf16x8*)(smem + ((ra*128 + kk*64 + (l>>4)*16) ^ ((ra & 7) << 4)));
        int rb = wn*64 + i*16 + (l & 15);
        bfv[i] = *(const bf16x8*)(smem + 16384 + ((rb*128 + kk*64 + (l>>4)*16) ^ ((rb & 7) << 4)));
      }
      for (int i = 0; i < 4; i++)
        for (int j = 0; j < 4; j++)
          acc[i][j] = __builtin_amdgcn_mfma_f32_16x16x32_bf16(af[i], bfv[j], acc[i][j], 0, 0, 0);
    }
  }
  // epilogue: exp -> e5m2 into swizzled LDS tile [128 R][128 Cc] bytes
  __syncthreads();
  u8* tile = (u8*)smem;
  for (int i = 0; i < 4; i++)
    for (int j = 0; j < 4; j++){
      int R  = wn*64 + j*16 + (l & 15);          // n-side row
      int Cc = wm*64 + i*16 + ((l >> 4) << 2);   // m-side col
      uint32_t wd =  f2e5m2(__expf((acc[i][j][0] - 1.f)*20.f))
                  | (f2e5m2(__expf((acc[i][j][1] - 1.f)*20.f)) << 8)
                  | (f2e5m2(__expf((acc[i][j][2] - 1.f)*20.f)) << 16)
                  | (f2e5m2(__expf((acc[i][j][3] - 1.f)*20.f)) << 24);
      *(uint32_t*)(tile + ((R*128 + Cc) ^ ((R & 7) << 4))) = wd;
    }
  __syncthreads();
  // coalesced write-out: K8[b][nt*128+R][mt*128 + 0..127], 128B contiguous per row
  size_t gb = ((size_t)(b*N_ + nt*128))*N_ + mt*128;
  for (int p = 0; p < 4; p++){
    int idx = p*256 + t;
    int R = idx >> 3, sl = idx & 7;
    uint4 vv = *(const uint4*)(tile + ((R*128 + sl*16) ^ ((R & 7) << 4)));
    *(uint4*)(K8 + gb + (size_t)R*N_ + sl*16) = vv;
  }
}

// -------------------------------- K4: Sinkhorn matvec on e5m2 K, out = marg/(K@x + 1e-8)
__global__ __launch_bounds__(256) void k_matvec(
    const u8* __restrict__ K8, const float* __restrict__ x,
    const float* __restrict__ q, float* __restrict__ out, int use_q){
  int w = threadIdx.x >> 6, l = threadIdx.x & 63;
  int row = blockIdx.x*4 + w;          // b*4096+m
  int b = row >> 12;
  const u8* kp = K8 + (size_t)row*N_;
  const float* xp = x + (size_t)b*N_;
  float s = 0.f;
  for (int it = 0; it < 8; it++){
    int n0 = it*512 + l*8;
    uint2 kv = *(const uint2*)(kp + n0);
    float4 x0 = *(const float4*)(xp + n0);
    float4 x1 = *(const float4*)(xp + n0 + 4);
    s += e5m2f( kv.x        & 0xff)*x0.x + e5m2f((kv.x >>  8) & 0xff)*x0.y
       + e5m2f((kv.x >> 16) & 0xff)*x0.z + e5m2f( kv.x >> 24        )*x0.w;
    s += e5m2f( kv.y        & 0xff)*x1.x + e5m2f((kv.y >>  8) & 0xff)*x1.y
       + e5m2f((kv.y >> 16) & 0xff)*x1.z + e5m2f( kv.y >> 24        )*x1.w;
  }
  for (int o = 32; o; o >>= 1) s += __shfl_down(s, o);
  if (l == 0){
    float marg = use_q ? q[row] : (1.f/(float)N_);
    out[row] = marg / (s + 1e-8f);
  }
}

// ----------------- K5: uS8[b][c][n] = e5m2((img*(1+g)+b) * u[n])  (CHW fp8)
__global__ __launch_bounds__(256) void k_uS(
    const float* __restrict__ img, const float* __restrict__ gamma, const float* __restrict__ beta,
    const float* __restrict__ u, u8* __restrict__ uS8){
  size_t i = ((size_t)blockIdx.x*256 + threadIdx.x)*4;
  int n = (int)(i & (N_ - 1));
  size_t bc = i >> 12;
  int b = (int)(bc >> 8);
  float gm = 1.f + gamma[bc];
  float bt = beta[bc];
  float4 v  = *(const float4*)(img + i);
  float4 uu = *(const float4*)(u + (size_t)b*N_ + n);
  uint32_t o =  f2e5m2((v.x*gm + bt)*uu.x)
             | (f2e5m2((v.y*gm + bt)*uu.y) << 8)
             | (f2e5m2((v.z*gm + bt)*uu.z) << 16)
             | (f2e5m2((v.w*gm + bt)*uu.w) << 24);
  *(uint32_t*)(uS8 + i) = o;
}

// --------- K6: split-K bf8xbf8 GEMM partials: part[ks][b][m][c] (f16)
__global__ __launch_bounds__(256) void k_fused_part(
    const u8* __restrict__ K8, const u8* __restrict__ uS8, _Float16* __restrict__ part){
  int ct = blockIdx.x & 1, ks = blockIdx.x >> 1;   // ct 0..1, ks 0..3
  int mt = blockIdx.y, b = blockIdx.z;
  __shared__ char smem[16384];   // As [128c][64] fp8 | Bs [128m][64] fp8
  int t = threadIdx.x, w = t >> 6, l = t & 63;
  int wc = w >> 1, wm = w & 1;
  f32x4 acc[4][4] = {};
  const u8* Ab = uS8 + ((size_t)(b*C_ + ct*128))*N_ + ks*1024;
  const u8* Bb = K8  + ((size_t)(b*N_ + mt*128))*N_ + ks*1024;
  for (int step = 0; step < 16; step++){
    __syncthreads();
    for (int r = 0; r < 2; r++){
      int off = r*4096 + t*16;
      int row = off >> 6;
      int col = (off & 63) ^ ((row & 3) << 4);
      gld_lds16(Ab + (size_t)row*N_ + step*64 + col, smem + off);
      gld_lds16(Bb + (size_t)row*N_ + step*64 + col, smem + 8192 + off);
    }
    __syncthreads();
    for (int kk = 0; kk < 2; kk++){
      long av[4], bv[4];
      for (int i = 0; i < 4; i++){
        int ra = wc*64 + i*16 + (l & 15);
        av[i] = *(const long*)(smem + ((ra*64 + kk*32 + (l>>4)*8) ^ ((ra & 3) << 4)));
        int rb = wm*64 + i*16 + (l & 15);
        bv[i] = *(const long*)(smem + 8192 + ((rb*64 + kk*32 + (l>>4)*8) ^ ((rb & 3) << 4)));
      }
      for (int i = 0; i < 4; i++)
        for (int j = 0; j < 4; j++)
          acc[i][j] = __builtin_amdgcn_mfma_f32_16x16x32_bf8_bf8(av[i], bv[j], acc[i][j], 0, 0, 0);
    }
  }
  _Float16* pp = part + ((size_t)(ks*2 + b))*N_*C_;
  for (int i = 0; i < 4; i++)
    for (int j = 0; j < 4; j++){
      int c0 = ct*128 + wc*64 + i*16 + ((l >> 4) << 2);
      int m  = mt*128 + wm*64 + j*16 + (l & 15);
      union { _Float16 h[4]; ushort4 u; } pk;
      pk.h[0] = (_Float16)acc[i][j][0];
      pk.h[1] = (_Float16)acc[i][j][1];
      pk.h[2] = (_Float16)acc[i][j][2];
      pk.h[3] = (_Float16)acc[i][j][3];
      *(ushort4*)(pp + (size_t)m*C_ + c0) = pk.u;
    }
}

// -------------------- K6b: reduce 4 split-K partials, scale by v[m], emit bf16 fused[n][c]
__global__ __launch_bounds__(256) void k_reduce(
    const _Float16* __restrict__ part, const float* __restrict__ vvec, u16* __restrict__ fused){
  int idx = blockIdx.x*256 + threadIdx.x;       // 2048 blocks -> 524288 threads
  int c0 = (idx & 63) * 4;
  int bm = idx >> 6;                            // b*4096 + m
  float vm = vvec[bm];
  float s0 = 0.f, s1 = 0.f, s2 = 0.f, s3 = 0.f;
  int b = bm >> 12, m = bm & 4095;
  for (int sp = 0; sp < 4; sp++){
    union { ushort4 u; _Float16 h[4]; } pk;
    pk.u = *(const ushort4*)(part + (((size_t)(sp*2 + b))*N_ + m)*C_ + c0);
    s0 += (float)pk.h[0]; s1 += (float)pk.h[1];
    s2 += (float)pk.h[2]; s3 += (float)pk.h[3];
  }
  ushort4 o;
  o.x = f2bf(s0*vm); o.y = f2bf(s1*vm);
  o.z = f2bf(s2*vm); o.w = f2bf(s3*vm);
  *(ushort4*)(fused + (size_t)bm*C_ + c0) = o;
}

// -------- K7: out[b][o][n] = img + sum_c Wo[o,c] fused[n,c] + bo  (direct-global frags)
__global__ __launch_bounds__(256) void k_outproj(
    const u16* __restrict__ fused, const u16* __restrict__ Wo_bf,
    const float* __restrict__ img, const float* __restrict__ bo, float* __restrict__ out){
  int nt = blockIdx.x, ot = blockIdx.y, b = blockIdx.z;
  int t = threadIdx.x, w = t >> 6, l = t & 63;
  int wm = w >> 1, wn = w & 1;
  f32x4 acc[4][2] = {};
  for (int kc = 0; kc < 8; kc++){
    bf16x8 af[4], bfv[2];
    for (int i = 0; i < 4; i++){
      int n = nt*128 + wm*64 + i*16 + (l & 15);
      af[i] = *(const bf16x8*)(fused + ((size_t)(b*N_ + n))*C_ + kc*32 + (l >> 4)*8);
    }
    for (int j = 0; j < 2; j++){
      int o = ot*64 + wn*32 + j*16 + (l & 15);
      bfv[j] = *(const bf16x8*)(Wo_bf + (size_t)o*C_ + kc*32 + (l >> 4)*8);
    }
    for (int i = 0; i < 4; i++)
      for (int j = 0; j < 2; j++)
        acc[i][j] = __builtin_amdgcn_mfma_f32_16x16x32_bf16(af[i], bfv[j], acc[i][j], 0, 0, 0);
  }
  for (int i = 0; i < 4; i++)
    for (int j = 0; j < 2; j++){
      int o = ot*64 + wn*32 + j*16 + (l & 15);
      int n = nt*128 + wm*64 + i*16 + ((l >> 4) << 2);
      size_t a = ((size_t)(b*C_ + o))*N_ + n;
      float4 iv = *(const float4*)(img + a);
      float bov = bo[o];
      float4 r;
      r.x = iv.x + acc[i][j][0] + bov;
      r.y = iv.y + acc[i][j][1] + bov;
      r.z = iv.z + acc[i][j][2] + bov;
      r.w = iv.w + acc[i][j][3] + bov;
      *(float4*)(out + a) = r;
    }
}

// ------------------------------- K7b: NCHW f32 -> NHWC bf16 transpose of out_feat
__global__ __launch_bounds__(256) void k_nhwc(const float* __restrict__ out, u16* __restrict__ out_bf){
  int b = blockIdx.y, n0 = blockIdx.x*64;
  __shared__ float tile[C_][65];
  int t = threadIdx.x;
  int x = t & 63, cb = t >> 6;
  for (int k = 0; k < 64; k++){
    int c = cb*64 + k;
    tile[c][x] = out[((size_t)(b*C_ + c))*N_ + n0 + x];
  }
  __syncthreads();
  for (int i = 0; i < 64; i++){
    int idx = i*256 + t;
    int c = idx & 255, nl = idx >> 8;
    out_bf[((size_t)(b*N_ + n0 + nl))*C_ + c] = f2bf(tile[c][nl]);
  }
}

// ---------------- K8: conv3x3 SAME via 9-shift implicit GEMM, h NHWC f32 (+bc1)
__global__ __launch_bounds__(256) void k_conv(
    const u16* __restrict__ out_bf, const u16* __restrict__ Wc1r,
    const float* __restrict__ bc1, float* __restrict__ h){
  int ot = blockIdx.x, pt = blockIdx.y, b = blockIdx.z;
  int t = threadIdx.x, w = t >> 6, l = t & 63;
  int wm = w >> 1, wn = w & 1;
  f32x4 acc[2][2] = {};
  int pbase = pt*64 + wn*32;
  for (int s = 0; s < 9; s++){
    int dy = s/3 - 1, dx = s - (s/3)*3 - 1;
    for (int kc = 0; kc < 8; kc++){
      bf16x8 af[2], bfv[2];
      for (int i = 0; i < 2; i++){
        int oc = ot*64 + wm*32 + i*16 + (l & 15);
        af[i] = *(const bf16x8*)(Wc1r + ((size_t)(s*OC_ + oc))*C_ + kc*32 + (l >> 4)*8);
      }
      for (int j = 0; j < 2; j++){
        int p = pbase + j*16 + (l & 15);
        int y = (p >> 6) + dy, x = (p & 63) + dx;
        bf16x8 v = {0,0,0,0,0,0,0,0};
        if ((unsigned)y < 64u && (unsigned)x < 64u)
          v = *(const bf16x8*)(out_bf + ((size_t)(b*N_ + y*64 + x))*C_ + kc*32 + (l >> 4)*8);
        bfv[j] = v;
      }
      for (int i = 0; i < 2; i++)
        for (int j = 0; j < 2; j++)
          acc[i][j] = __builtin_amdgcn_mfma_f32_16x16x32_bf16(af[i], bfv[j], acc[i][j], 0, 0, 0);
    }
  }
  for (int i = 0; i < 2; i++)
    for (int j = 0; j < 2; j++){
      int p = pt*64 + wn*32 + j*16 + (l & 15);
      int oc = ot*64 + wm*32 + i*16 + ((l >> 4) << 2);
      float4 bc = *(const float4*)(bc1 + oc);
      float4 r;
      r.x = acc[i][j][0] + bc.x;
      r.y = acc[i][j][1] + bc.y;
      r.z = acc[i][j][2] + bc.z;
      r.w = acc[i][j][3] + bc.w;
      *(float4*)(h + ((size_t)(b*N_ + p))*OC_ + oc) = r;
    }
}

// -------------------------------------------- K9a: BN partial sums over 128-row chunks
__global__ __launch_bounds__(256) void k_stats(
    const float* __restrict__ h, float* __restrict__ pSum, float* __restrict__ pSsq){
  int blk = blockIdx.x;     // 64 blocks x 128 rows
  int t = threadIdx.x; int c = t & 127, half = t >> 7;
  __shared__ float s1[256], s2[256];
  float a = 0.f, b2 = 0.f;
  int r0 = blk*128 + half*64;
  for (int r = 0; r < 64; r++){
    float v = h[((size_t)(r0 + r))*OC_ + c];
    a += v; b2 += v*v;
  }
  s1[t] = a; s2[t] = b2;
  __syncthreads();
  if (t < 128){
    pSum[blk*128 + c] = s1[t] + s1[t + 128];
    pSsq[blk*128 + c] = s2[t] + s2[t + 128];
  }
}

// ------------------------------- K9b: finalize BN -> scale/shift per channel
__global__ void k_bnfin(
    const float* __restrict__ pSum, const float* __restrict__ pSsq,
    const float* __restrict__ bn_g, const float* __restrict__ bn_b, float* __restrict__ scsh){
  int c = threadIdx.x;   // 128
  float s = 0.f, ss = 0.f;
  for (int k = 0; k < 64; k++){ s += pSum[k*128 + c]; ss += pSsq[k*128 + c]; }
  float m = s * (1.f/8192.f);
  float var = ss * (1.f/8192.f) - m*m;
  float sc = bn_g[c] * rsqrtf(var + 1e-5f);
  scsh[c*2]   = sc;
  scsh[c*2+1] = bn_b[c] - m*sc;
}

// ------------------------- K10: relu(h*sc+sh) -> 1x1 conv (2 ch) -> heatmap NCHW
__global__ __launch_bounds__(256) void k_head(
    const float* __restrict__ h, const float* __restrict__ scsh,
    const float* __restrict__ Wc2, const float* __restrict__ bc2, float* __restrict__ hm){
  __shared__ float sc[128], sh[128], w0[128], w1[128];
  int t = threadIdx.x;
  if (t < 128){
    sc[t] = scsh[t*2]; sh[t] = scsh[t*2+1];
    w0[t] = Wc2[t];    w1[t] = Wc2[128 + t];
  }
  __syncthreads();
  int n = blockIdx.x*256 + t;          // 0..8191 = b*4096+p
  const float* hp = h + (size_t)n*OC_;
  float a0 = bc2[0], a1 = bc2[1];
  for (int c4 = 0; c4 < 32; c4++){
    float4 hv = *(const float4*)(hp + c4*4);
    int c = c4*4;
    float r;
    r = fmaxf(hv.x*sc[c]   + sh[c],   0.f); a0 += w0[c]*r;   a1 += w1[c]*r;
    r = fmaxf(hv.y*sc[c+1] + sh[c+1], 0.f); a0 += w0[c+1]*r; a1 += w1[c+1]*r;
    r = fmaxf(hv.z*sc[c+2] + sh[c+2], 0.f); a0 += w0[c+2]*r; a1 += w1[c+2]*r;
    r = fmaxf(hv.w*sc[c+3] + sh[c+3], 0.f); a0 += w0[c+3]*r; a1 += w1[c+3]*r;
  }
  int b = n >> 12, p = n & 4095;
  hm[((size_t)(b*2 + 0))*N_ + p] = a0;
  hm[((size_t)(b*2 + 1))*N_ + p] = a1;
}

// ================================================================ launcher
extern "C" void kernel_launch(void* const* d_in, const int* in_sizes, int n_in,
                              void* d_out, int out_size, void* d_ws, size_t ws_size,
                              hipStream_t stream){
  const float* img  = (const float*)d_in[0];
  const float* txt  = (const float*)d_in[1];
  const float* dens = (const float*)d_in[2];
  const float* Wt   = (const float*)d_in[3];
  const float* bt   = (const float*)d_in[4];
  const float* Wg   = (const float*)d_in[5];
  const float* bg   = (const float*)d_in[6];
  const float* Wb   = (const float*)d_in[7];
  const float* bb   = (const float*)d_in[8];
  const float* Wo   = (const float*)d_in[9];
  const float* bo   = (const float*)d_in[10];
  const float* Wc1  = (const float*)d_in[11];
  const float* bc1  = (const float*)d_in[12];
  const float* bng  = (const float*)d_in[13];
  const float* bnb  = (const float*)d_in[14];
  const float* Wc2  = (const float*)d_in[15];
  const float* bc2  = (const float*)d_in[16];

  char* ws = (char*)d_ws;
  // workspace layout (bytes), no overlays needed (~70 MB total)
  u8*       K8     = (u8*)      (ws + 0);           // 33,554,432
  u16*      Sn     = (u16*)     (ws + 33554432);    //  4,194,304
  u8*       uS8    = (u8*)      (ws + 37748736);    //  2,097,152
  _Float16* partH  = (_Float16*)(ws + 39845888);    // 16,777,216
  u16*      fused  = (u16*)     (ws + 56623104);    //  4,194,304
  u16*      out_bf = (u16*)     (ws + 60817408);    //  4,194,304
  float*    hbuf   = (float*)   (ws + 65011712);    //  4,194,304
  float*    gamma  = (float*)   (ws + 69206016);    //      2,048
  float*    beta   = (float*)   (ws + 69208064);    //      2,048
  float*    q      = (float*)   (ws + 69210112);    //     32,768
  float*    u      = (float*)   (ws + 69242880);    //     32,768
  float*    v      = (float*)   (ws + 69275648);    //     32,768
  u16*      Wo_bf  = (u16*)     (ws + 69308416);    //    131,072
  u16*      Wc1r   = (u16*)     (ws + 69439488);    //    589,824
  float*    pSum   = (float*)   (ws + 70029312);    //     32,768
  float*    pSsq   = (float*)   (ws + 70062080);    //     32,768
  float*    scsh   = (float*)   (ws + 70094848);    //      1,024

  float* outp = (float*)d_out;                 // [2,256,64,64]
  float* hm   = outp + 2*C_*N_;                // [2,2,64,64]

  k_film  <<<2, 256, 0, stream>>>(txt, Wt, bt, Wg, bg, Wb, bb, gamma, beta);
  k_build <<<dim3(64,2), 256, 0, stream>>>(img, gamma, beta, Sn);
  k_qinit <<<2, 256, 0, stream>>>(dens, q, u);
  k_repack<<<1152, 256, 0, stream>>>(Wo, Wc1, Wo_bf, Wc1r);
  k_simK  <<<dim3(32,32,2), 256, 0, stream>>>(Sn, K8);
  for (int it = 0; it < 3; it++){
    k_matvec<<<2048, 256, 0, stream>>>(K8, u, q, v, 1);
    k_matvec<<<2048, 256, 0, stream>>>(K8, v, q, u, 0);
  }
  k_uS        <<<2048, 256, 0, stream>>>(img, gamma, beta, u, uS8);
  k_fused_part<<<dim3(8,32,2), 256, 0, stream>>>(K8, uS8, partH);
  k_reduce    <<<2048, 256, 0, stream>>>(partH, v, fused);
  k_outproj   <<<dim3(32,4,2), 256, 0, stream>>>(fused, Wo_bf, img, bo, outp);
  k_nhwc      <<<dim3(64,2), 256, 0, stream>>>(outp, out_bf);
  k_conv      <<<dim3(2,64,2), 256, 0, stream>>>(out_bf, Wc1r, bc1, hbuf);
  k_stats     <<<64, 256, 0, stream>>>(hbuf, pSum, pSsq);
  k_bnfin     <<<1, 128, 0, stream>>>(pSum, pSsq, bng, bnb, scsh);
  k_head      <<<32, 256, 0, stream>>>(hbuf, scsh, Wc2, bc2, hm);
}